// Round 1
// baseline (718.398 us; speedup 1.0000x reference)
//
#include <hip/hip_runtime.h>
#include <math.h>

// Problem constants (from reference setup_inputs)
#define BB 32
#define SS 2048
#define NN 16
#define DD 128
#define ND (NN * DD)      // 2048 floats per (b, s) slice
#define ND4 (ND / 4)      // 512 float4 per slice
#define HH 64             // hidden dim

#define CS 64             // s-chunk per block in reduce kernel
#define NCHUNK (SS / CS)  // 32 chunks

// ---------------------------------------------------------------------------
// Kernel 1: mean over S axis via per-chunk partial sums + float atomicAdd.
// grid = BB * NCHUNK blocks, 256 threads. Each thread owns 2 float4 columns
// and streams CS s-slices (coalesced global_load_dwordx4), then does 8
// atomicAdds of the pre-scaled partial into the mean buffer (in d_ws).
// ---------------------------------------------------------------------------
__global__ __launch_bounds__(256) void reduce_mean_kernel(
    const float* __restrict__ x, float* __restrict__ mean) {
  const int blk   = blockIdx.x;
  const int b     = blk >> 5;        // / NCHUNK (=32)
  const int chunk = blk & 31;        // % NCHUNK
  const int t     = threadIdx.x;

  const float4* xb = (const float4*)x +
                     (size_t)b * SS * ND4 + (size_t)chunk * CS * ND4;

  const int c0 = t;        // float4 column 0..255
  const int c1 = t + 256;  // float4 column 256..511

  float4 a0 = make_float4(0.f, 0.f, 0.f, 0.f);
  float4 a1 = make_float4(0.f, 0.f, 0.f, 0.f);

#pragma unroll 4
  for (int s = 0; s < CS; ++s) {
    const float4 v0 = xb[(size_t)s * ND4 + c0];
    const float4 v1 = xb[(size_t)s * ND4 + c1];
    a0.x += v0.x; a0.y += v0.y; a0.z += v0.z; a0.w += v0.w;
    a1.x += v1.x; a1.y += v1.y; a1.z += v1.z; a1.w += v1.w;
  }

  const float inv = 1.0f / (float)SS;
  float* m = mean + (size_t)b * ND;
  atomicAdd(&m[c0 * 4 + 0], a0.x * inv);
  atomicAdd(&m[c0 * 4 + 1], a0.y * inv);
  atomicAdd(&m[c0 * 4 + 2], a0.z * inv);
  atomicAdd(&m[c0 * 4 + 3], a0.w * inv);
  atomicAdd(&m[c1 * 4 + 0], a1.x * inv);
  atomicAdd(&m[c1 * 4 + 1], a1.y * inv);
  atomicAdd(&m[c1 * 4 + 2], a1.z * inv);
  atomicAdd(&m[c1 * 4 + 3], a1.w * inv);
}

// ---------------------------------------------------------------------------
// Kernel 2: per-pair tiny MLP. One 64-lane wave per ordered (b, i, j).
// Waves with i >= j exit immediately (wave-uniform branch). Lane k computes
// hidden unit k: acc = b1[k] + sum_d mean_i[d]*W1[d][k] + mean_j[d]*W1[D+d][k]
// (W1 column loads are lane-coalesced; mean loads are wave-uniform L1
// broadcasts). Exact-erf GELU, then 64-lane shuffle reduce of h_k*W2[k];
// lane 0 applies sigmoid and writes out[b,i,j] and out[b,j,i].
// Diagonal stays 0 from the preceding memset.
// ---------------------------------------------------------------------------
__global__ __launch_bounds__(256) void pair_mlp_kernel(
    const float* __restrict__ mean, const float* __restrict__ W1,
    const float* __restrict__ b1, const float* __restrict__ W2,
    const float* __restrict__ b2, float* __restrict__ out) {
  const int wave = (blockIdx.x * 256 + threadIdx.x) >> 6;  // 0..8191
  const int lane = threadIdx.x & 63;

  const int b   = wave >> 8;   // / 256
  const int rem = wave & 255;
  const int i   = rem >> 4;
  const int j   = rem & 15;
  if (i >= j) return;  // wave-uniform

  const float* mi = mean + (size_t)b * ND + i * DD;
  const float* mj = mean + (size_t)b * ND + j * DD;

  float acc = b1[lane];
#pragma unroll 8
  for (int d = 0; d < DD; ++d) {
    const float wi = W1[d * HH + lane];
    const float wj = W1[(DD + d) * HH + lane];
    acc = fmaf(mi[d], wi, acc);
    acc = fmaf(mj[d], wj, acc);
  }

  // exact GELU: 0.5*x*(1+erf(x/sqrt(2)))
  const float hk = 0.5f * acc * (1.0f + erff(acc * 0.7071067811865476f));

  float v = hk * W2[lane];
#pragma unroll
  for (int off = 32; off > 0; off >>= 1) v += __shfl_down(v, off, 64);

  if (lane == 0) {
    const float s = 1.0f / (1.0f + expf(-(v + b2[0])));
    out[(size_t)b * NN * NN + i * NN + j] = s;
    out[(size_t)b * NN * NN + j * NN + i] = s;
  }
}

extern "C" void kernel_launch(void* const* d_in, const int* in_sizes, int n_in,
                              void* d_out, int out_size, void* d_ws,
                              size_t ws_size, hipStream_t stream) {
  const float* x  = (const float*)d_in[0];  // [B,S,N,D]
  const float* W1 = (const float*)d_in[1];  // [2D,H]
  const float* b1 = (const float*)d_in[2];  // [H]
  const float* W2 = (const float*)d_in[3];  // [H,1]
  const float* b2 = (const float*)d_in[4];  // [1]
  float* out = (float*)d_out;               // [B,N,N] = 8192 floats
  float* mean = (float*)d_ws;               // B*ND = 65536 floats (256 KiB)

  // ws and out are re-poisoned (0xAA) before every timed call.
  hipMemsetAsync(mean, 0, (size_t)BB * ND * sizeof(float), stream);

  reduce_mean_kernel<<<BB * NCHUNK, 256, 0, stream>>>(x, mean);

  hipMemsetAsync(out, 0, (size_t)BB * NN * NN * sizeof(float), stream);

  // 8192 waves total, 4 waves (256 threads) per block -> 2048 blocks
  pair_mlp_kernel<<<2048, 256, 0, stream>>>(mean, W1, b1, W2, b2, out);
}

// Round 2
// 701.399 us; speedup vs baseline: 1.0242x; 1.0242x over previous
//
#include <hip/hip_runtime.h>
#include <math.h>

// Problem constants (from reference setup_inputs)
#define BB 32
#define SS 2048
#define NN 16
#define DD 128
#define ND (NN * DD)      // 2048 floats per (b, s) slice
#define ND4 (ND / 4)      // 512 float4 per slice
#define HH 64             // hidden dim

#define CS 64             // s-chunk per block in reduce kernel
#define NCHUNK (SS / CS)  // 32 chunks

// ws layout: [0, 256 KiB)  mean   (BB*ND floats)
//            [16 MiB, ...) partial (BB*NCHUNK*ND floats = 8 MiB)
#define PARTIAL_OFF_BYTES (16u * 1024u * 1024u)

// ---------------------------------------------------------------------------
// Kernel A: per-(b, s-chunk) partial sums, PLAIN float4 stores (no init, no
// atomics). grid = BB*NCHUNK = 1024 blocks, 256 threads. Each thread owns 2
// float4 columns and streams CS=64 s-slices (coalesced dwordx4, 1 KiB/wave).
// ---------------------------------------------------------------------------
__global__ __launch_bounds__(256) void partial_sum_kernel(
    const float* __restrict__ x, float4* __restrict__ partial) {
  const int blk   = blockIdx.x;          // b*32 + chunk
  const int b     = blk >> 5;
  const int chunk = blk & 31;
  const int t     = threadIdx.x;

  const float4* xb = (const float4*)x +
                     (size_t)b * SS * ND4 + (size_t)chunk * CS * ND4;

  const int c0 = t;
  const int c1 = t + 256;

  float4 a0 = make_float4(0.f, 0.f, 0.f, 0.f);
  float4 a1 = make_float4(0.f, 0.f, 0.f, 0.f);

#pragma unroll 4
  for (int s = 0; s < CS; ++s) {
    const float4 v0 = xb[(size_t)s * ND4 + c0];
    const float4 v1 = xb[(size_t)s * ND4 + c1];
    a0.x += v0.x; a0.y += v0.y; a0.z += v0.z; a0.w += v0.w;
    a1.x += v1.x; a1.y += v1.y; a1.z += v1.z; a1.w += v1.w;
  }

  float4* p = partial + (size_t)blk * ND4;
  p[c0] = a0;
  p[c1] = a1;
}

// ---------------------------------------------------------------------------
// Kernel B: finalize mean[b][e] = (1/S) * sum_{chunk} partial[b][chunk][e].
// 16384 float4 elements total -> 64 blocks x 256 threads, one float4 each.
// Reads 8 MiB (L2-resident), writes 256 KiB.
// ---------------------------------------------------------------------------
__global__ __launch_bounds__(256) void finalize_mean_kernel(
    const float4* __restrict__ partial, float4* __restrict__ mean) {
  const int g = blockIdx.x * 256 + threadIdx.x;  // 0..16383
  const int b = g >> 9;        // / 512
  const int c = g & 511;       // float4 column within slice

  float4 a = make_float4(0.f, 0.f, 0.f, 0.f);
#pragma unroll
  for (int chunk = 0; chunk < NCHUNK; ++chunk) {
    const float4 v = partial[((size_t)(b * NCHUNK + chunk)) * ND4 + c];
    a.x += v.x; a.y += v.y; a.z += v.z; a.w += v.w;
  }
  const float inv = 1.0f / (float)SS;
  a.x *= inv; a.y *= inv; a.z *= inv; a.w *= inv;
  mean[(size_t)b * ND4 + c] = a;
}

// ---------------------------------------------------------------------------
// Kernel C: per-pair tiny MLP. One 64-lane wave per unordered pair (i<j):
// 120 pairs * 32 batches = 3840 waves -> 960 blocks x 256 threads.
// Lane k computes hidden unit k (W1 column loads lane-coalesced; mean loads
// wave-uniform L1 broadcasts), exact-erf GELU, 64-lane shuffle reduce for the
// W2 dot, lane 0 writes sigmoid to out[b,i,j] and out[b,j,i]. Pair-0 wave of
// each b also zeroes the 16 diagonal entries (out is poisoned 0xAA, never
// pre-memset).
// ---------------------------------------------------------------------------
__global__ __launch_bounds__(256) void pair_mlp_kernel(
    const float* __restrict__ mean, const float* __restrict__ W1,
    const float* __restrict__ b1, const float* __restrict__ W2,
    const float* __restrict__ b2, float* __restrict__ out) {
  const int wave = (blockIdx.x * 256 + threadIdx.x) >> 6;  // 0..3839
  const int lane = threadIdx.x & 63;

  const int b = wave / 120;
  int k = wave - b * 120;  // triangular pair index, i<j

  // decode (i, j) from k: k = sum_{r<i}(15-r) + (j-i-1)
  int i = 0;
#pragma unroll
  for (int r = 0; r < 15; ++r) {
    const bool adv = k >= (15 - i);
    if (adv) { k -= (15 - i); i++; }
  }
  const int j = i + 1 + k;

  float* ob = out + (size_t)b * NN * NN;
  if (wave - b * 120 == 0 && lane < NN) {  // recompute orig k cheaply
  }
  // diagonal zeros: pair-index 0 wave of each b
  const int pk = wave - b * 120;

  const float* mi = mean + (size_t)b * ND + i * DD;
  const float* mj = mean + (size_t)b * ND + j * DD;

  float acc = b1[lane];
#pragma unroll 8
  for (int d = 0; d < DD; ++d) {
    const float wi = W1[d * HH + lane];
    const float wj = W1[(DD + d) * HH + lane];
    acc = fmaf(mi[d], wi, acc);
    acc = fmaf(mj[d], wj, acc);
  }

  // exact GELU: 0.5*x*(1+erf(x/sqrt(2)))
  const float hk = 0.5f * acc * (1.0f + erff(acc * 0.7071067811865476f));

  float v = hk * W2[lane];
#pragma unroll
  for (int off = 32; off > 0; off >>= 1) v += __shfl_down(v, off, 64);

  if (lane == 0) {
    const float s = 1.0f / (1.0f + expf(-(v + b2[0])));
    ob[i * NN + j] = s;
    ob[j * NN + i] = s;
  }
  if (pk == 0 && lane < NN) {
    ob[lane * NN + lane] = 0.0f;
  }
}

extern "C" void kernel_launch(void* const* d_in, const int* in_sizes, int n_in,
                              void* d_out, int out_size, void* d_ws,
                              size_t ws_size, hipStream_t stream) {
  const float* x  = (const float*)d_in[0];  // [B,S,N,D]
  const float* W1 = (const float*)d_in[1];  // [2D,H]
  const float* b1 = (const float*)d_in[2];  // [H]
  const float* W2 = (const float*)d_in[3];  // [H,1]
  const float* b2 = (const float*)d_in[4];  // [1]
  float* out = (float*)d_out;               // [B,N,N] = 8192 floats

  float*  mean    = (float*)d_ws;                                   // 256 KiB
  float4* partial = (float4*)((char*)d_ws + PARTIAL_OFF_BYTES);     // 8 MiB

  partial_sum_kernel<<<BB * NCHUNK, 256, 0, stream>>>(x, partial);
  finalize_mean_kernel<<<64, 256, 0, stream>>>(partial, (float4*)mean);
  pair_mlp_kernel<<<960, 256, 0, stream>>>(mean, W1, b1, W2, b2, out);
}